// Round 2
// baseline (119.473 us; speedup 1.0000x reference)
//
#include <hip/hip_runtime.h>
#include <hip/hip_bf16.h>

// SelfContrastiveLoss: loss over E = exp(qn @ kn^T / T), B=8192, D=256.
// Only rowsum(E), colsum(E), diag d_i are needed -> fused GEMM+exp+reduce.
// R2: m97-structure GEMM (global_load_lds width=16, linear LDS), memset fused
//     into norm kernel, loss kernel parallelized (16 blocks + atomicAdd).
//
// ws layout:
//   [0,            4 MB)  qn bf16   (8192*256*2)
//   [4 MB,         8 MB)  kn bf16
//   [8 MB,       +32 KB)  diag  d_i = exp(dot(qn_i,kn_i)/T)  fp32
//   [.. +32 KB]           rowsum fp32
//   [.. +32 KB]           colsum fp32

#define NB 8192
#define ND 256

constexpr float TEMP_INV = 20.0f;   // 1 / 0.05
constexpr float EPS = 1e-5f;

typedef float f32x4 __attribute__((ext_vector_type(4)));
typedef short s16x8 __attribute__((ext_vector_type(8)));

#define GLOAD_LDS16(g, l)                                                  \
  __builtin_amdgcn_global_load_lds(                                        \
      (const __attribute__((address_space(1))) unsigned int*)(g),          \
      (__attribute__((address_space(3))) unsigned int*)(l), 16, 0, 0)

// ---------------- kernel 1: row L2-normalize -> bf16, fp32 diag, zero accums
__global__ __launch_bounds__(256) void norm_diag_kernel(
    const float* __restrict__ q, const float* __restrict__ k,
    ushort* __restrict__ qn, ushort* __restrict__ kn, float* __restrict__ diag,
    float* __restrict__ rowcol /*rowsum||colsum, 2*NB floats*/,
    float* __restrict__ out) {
  // fold the accumulator zeroing into this kernel (saves a memset launch)
  if (blockIdx.x < 64) rowcol[blockIdx.x * 256 + threadIdx.x] = 0.f;
  if (blockIdx.x == 64 && threadIdx.x == 0) out[0] = 0.f;

  const int wave = threadIdx.x >> 6;
  const int lane = threadIdx.x & 63;
  const int row = blockIdx.x * 4 + wave;          // one wave per row
  const float4* q4 = reinterpret_cast<const float4*>(q + (size_t)row * ND);
  const float4* k4 = reinterpret_cast<const float4*>(k + (size_t)row * ND);
  float4 qv = q4[lane];                            // 4 floats/lane * 64 = 256
  float4 kv = k4[lane];
  float sq = qv.x * qv.x + qv.y * qv.y + qv.z * qv.z + qv.w * qv.w;
  float sk = kv.x * kv.x + kv.y * kv.y + kv.z * kv.z + kv.w * kv.w;
  float dp = qv.x * kv.x + qv.y * kv.y + qv.z * kv.z + qv.w * kv.w;
#pragma unroll
  for (int m = 1; m < 64; m <<= 1) {
    sq += __shfl_xor(sq, m);
    sk += __shfl_xor(sk, m);
    dp += __shfl_xor(dp, m);
  }
  const float iq = 1.0f / fmaxf(sqrtf(sq), 1e-12f);   // F.normalize eps
  const float ik = 1.0f / fmaxf(sqrtf(sk), 1e-12f);
  union { ushort4 u; __hip_bfloat16 h[4]; } pq, pk;
  pq.h[0] = __float2bfloat16(qv.x * iq);
  pq.h[1] = __float2bfloat16(qv.y * iq);
  pq.h[2] = __float2bfloat16(qv.z * iq);
  pq.h[3] = __float2bfloat16(qv.w * iq);
  pk.h[0] = __float2bfloat16(kv.x * ik);
  pk.h[1] = __float2bfloat16(kv.y * ik);
  pk.h[2] = __float2bfloat16(kv.z * ik);
  pk.h[3] = __float2bfloat16(kv.w * ik);
  reinterpret_cast<ushort4*>(qn)[(size_t)row * (ND / 4) + lane] = pq.u;
  reinterpret_cast<ushort4*>(kn)[(size_t)row * (ND / 4) + lane] = pk.u;
  if (lane == 0) diag[row] = __expf(dp * iq * ik * TEMP_INV);  // exact fp32 diag
}

// ---------------- kernel 2: fused bf16 MFMA GEMM + exp + row/col reduce ------
// m97 structure: 128x128 tile, BK=64, linear LDS, global_load_lds width=16.
#define BM 128
#define BN 128
#define BK 64

__global__ __launch_bounds__(256) void gemm_exp_reduce_kernel(
    const ushort* __restrict__ qn, const ushort* __restrict__ kn,
    float* __restrict__ rowsum, float* __restrict__ colsum) {
  __shared__ ushort As[BM][BK];   // linear: global_load_lds dest must be
  __shared__ ushort Bs[BN][BK];   // wave-uniform base + lane*16, no pad
  const int tid  = threadIdx.x;
  const int lane = tid & 63;
  const int wave = tid >> 6;          // 4 waves: 2x2 of 64x64 sub-tiles
  const int wr = wave >> 1;
  const int wc = wave & 1;
  const int l15 = lane & 15;
  const int lhi = lane >> 4;
  const int brow = blockIdx.y * BM;
  const int bcol = blockIdx.x * BN;

  f32x4 acc[4][4];
#pragma unroll
  for (int mf = 0; mf < 4; ++mf)
#pragma unroll
    for (int nf = 0; nf < 4; ++nf)
      acc[mf][nf] = (f32x4){0.f, 0.f, 0.f, 0.f};

  ushort* AsF = &As[0][0];
  ushort* BsF = &Bs[0][0];

#pragma unroll
  for (int kt = 0; kt < ND; kt += BK) {
    // stage 128x64 shorts of each matrix = 16 KB = 16 wave-chunks of 1 KB.
    // 4 waves x 4 calls x (A,B). Per call: wave-chunk cb covers flat shorts
    // [cb*512, cb*512+512) = rows [cb*8, cb*8+8); lane l -> chunk fc=cb*64+l.
#pragma unroll
    for (int i = 0; i < 4; ++i) {
      const int cb = wave * 4 + i;
      const int fc = cb * 64 + lane;
      const int r  = fc >> 3;             // row within tile
      const int kc = (fc & 7) * 8;        // k-offset (shorts)
      GLOAD_LDS16(&qn[(size_t)(brow + r) * ND + kt + kc], AsF + (size_t)cb * 512);
      GLOAD_LDS16(&kn[(size_t)(bcol + r) * ND + kt + kc], BsF + (size_t)cb * 512);
    }
    __syncthreads();   // compiler drains vmcnt(0) before s_barrier
#pragma unroll
    for (int ks = 0; ks < 2; ++ks) {
      s16x8 af[4], bfrag[4];
#pragma unroll
      for (int mf = 0; mf < 4; ++mf)
        af[mf] = *reinterpret_cast<const s16x8*>(&As[wr * 64 + mf * 16 + l15][ks * 32 + lhi * 8]);
#pragma unroll
      for (int nf = 0; nf < 4; ++nf)
        bfrag[nf] = *reinterpret_cast<const s16x8*>(&Bs[wc * 64 + nf * 16 + l15][ks * 32 + lhi * 8]);
#pragma unroll
      for (int mf = 0; mf < 4; ++mf)
#pragma unroll
        for (int nf = 0; nf < 4; ++nf)
          acc[mf][nf] = __builtin_amdgcn_mfma_f32_16x16x32_bf16(
              af[mf], bfrag[nf], acc[mf][nf], 0, 0, 0);
    }
    __syncthreads();
  }

  // epilogue: E = exp(S / T), in-register
#pragma unroll
  for (int mf = 0; mf < 4; ++mf)
#pragma unroll
    for (int nf = 0; nf < 4; ++nf)
#pragma unroll
      for (int j = 0; j < 4; ++j)
        acc[mf][nf][j] = __expf(acc[mf][nf][j] * TEMP_INV);

  // C/D layout (m89-verified): col = lane&15, row = (lane>>4)*4 + j
  // row sums: sum over nf in-register, then over the 16 cols (lane bits 0-3)
#pragma unroll
  for (int mf = 0; mf < 4; ++mf) {
#pragma unroll
    for (int j = 0; j < 4; ++j) {
      float v = acc[mf][0][j] + acc[mf][1][j] + acc[mf][2][j] + acc[mf][3][j];
      v += __shfl_xor(v, 1);
      v += __shfl_xor(v, 2);
      v += __shfl_xor(v, 4);
      v += __shfl_xor(v, 8);
      if (l15 == 0) {
        const int row = brow + wr * 64 + mf * 16 + lhi * 4 + j;
        atomicAdd(&rowsum[row], v);
      }
    }
  }
  // col sums: sum over mf,j in-register, then over rows (lane bits 4-5)
#pragma unroll
  for (int nf = 0; nf < 4; ++nf) {
    float c = 0.f;
#pragma unroll
    for (int mf = 0; mf < 4; ++mf)
#pragma unroll
      for (int j = 0; j < 4; ++j)
        c += acc[mf][nf][j];
    c += __shfl_xor(c, 16);
    c += __shfl_xor(c, 32);
    if (lhi == 0) {
      const int col = bcol + wc * 64 + nf * 16 + l15;
      atomicAdd(&colsum[col], c);
    }
  }
}

// ---------------- kernel 3: final scalar loss (parallel, 16 blocks) ----------
__global__ __launch_bounds__(256) void loss_kernel(
    const float* __restrict__ diag, const float* __restrict__ rowsum,
    const float* __restrict__ colsum, float* __restrict__ out) {
  float acc = 0.f;
  for (int i = blockIdx.x * 256 + threadIdx.x; i < NB; i += 16 * 256) {
    const float d = diag[i];
    acc -= __logf(d / rowsum[i] + EPS);
    acc -= __logf(d / colsum[i] + EPS);
  }
#pragma unroll
  for (int m = 1; m < 64; m <<= 1) acc += __shfl_xor(acc, m);
  __shared__ float ls[4];
  const int wave = threadIdx.x >> 6;
  if ((threadIdx.x & 63) == 0) ls[wave] = acc;
  __syncthreads();
  if (threadIdx.x == 0)
    atomicAdd(out, (ls[0] + ls[1] + ls[2] + ls[3]) * (1.0f / NB));
}

extern "C" void kernel_launch(void* const* d_in, const int* in_sizes, int n_in,
                              void* d_out, int out_size, void* d_ws, size_t ws_size,
                              hipStream_t stream) {
  const float* q = (const float*)d_in[0];
  const float* k = (const float*)d_in[1];
  char* ws = (char*)d_ws;
  ushort* qn   = (ushort*)ws;                                   // 4 MB
  ushort* kn   = (ushort*)(ws + (size_t)NB * ND * 2);           // 4 MB
  float*  diag = (float*)(ws + (size_t)NB * ND * 4);            // 32 KB
  float*  rowsum = diag + NB;                                   // 32 KB
  float*  colsum = rowsum + NB;                                 // 32 KB
  float*  out = (float*)d_out;

  norm_diag_kernel<<<NB / 4, 256, 0, stream>>>(q, k, qn, kn, diag, rowsum, out);
  gemm_exp_reduce_kernel<<<dim3(NB / BN, NB / BM), 256, 0, stream>>>(
      qn, kn, rowsum, colsum);
  loss_kernel<<<16, 256, 0, stream>>>(diag, rowsum, colsum, out);
}

// Round 3
// 119.310 us; speedup vs baseline: 1.0014x; 1.0014x over previous
//
#include <hip/hip_runtime.h>
#include <hip/hip_bf16.h>

// SelfContrastiveLoss: loss over E = exp(qn @ kn^T / T), B=8192, D=256.
// R3: 256x256 8-wave GEMM (M_rep=8,N_rep=4 -> 43.7 FLOP/LDS-byte), dbuf LDS
//     128KB, counted-vmcnt 2-phase schedule (raw s_barrier, vmcnt(8) mid-loop),
//     XOR chunk-swizzle both-sides (pre-swizzled global src + swizzled read).
//
// ws layout: qn bf16 4MB | kn bf16 4MB | diag 32KB | rowsum 32KB | colsum 32KB

#define NB 8192
#define ND 256

constexpr float TEMP_INV = 20.0f;   // 1 / 0.05
constexpr float EPS = 1e-5f;

typedef float f32x4 __attribute__((ext_vector_type(4)));
typedef short s16x8 __attribute__((ext_vector_type(8)));

#define GLOAD_LDS16(g, l)                                                  \
  __builtin_amdgcn_global_load_lds(                                        \
      (const __attribute__((address_space(1))) unsigned int*)(g),          \
      (__attribute__((address_space(3))) unsigned int*)(l), 16, 0, 0)

// ---------------- kernel 1: row L2-normalize -> bf16, fp32 diag, zero accums
__global__ __launch_bounds__(256) void norm_diag_kernel(
    const float* __restrict__ q, const float* __restrict__ k,
    ushort* __restrict__ qn, ushort* __restrict__ kn, float* __restrict__ diag,
    float* __restrict__ rowcol /*rowsum||colsum, 2*NB floats*/,
    float* __restrict__ out) {
  if (blockIdx.x < 64) rowcol[blockIdx.x * 256 + threadIdx.x] = 0.f;
  if (blockIdx.x == 64 && threadIdx.x == 0) out[0] = 0.f;

  const int wave = threadIdx.x >> 6;
  const int lane = threadIdx.x & 63;
  const int row = blockIdx.x * 4 + wave;          // one wave per row
  const float4* q4 = reinterpret_cast<const float4*>(q + (size_t)row * ND);
  const float4* k4 = reinterpret_cast<const float4*>(k + (size_t)row * ND);
  float4 qv = q4[lane];
  float4 kv = k4[lane];
  float sq = qv.x * qv.x + qv.y * qv.y + qv.z * qv.z + qv.w * qv.w;
  float sk = kv.x * kv.x + kv.y * kv.y + kv.z * kv.z + kv.w * kv.w;
  float dp = qv.x * kv.x + qv.y * kv.y + qv.z * kv.z + qv.w * kv.w;
#pragma unroll
  for (int m = 1; m < 64; m <<= 1) {
    sq += __shfl_xor(sq, m);
    sk += __shfl_xor(sk, m);
    dp += __shfl_xor(dp, m);
  }
  const float iq = 1.0f / fmaxf(sqrtf(sq), 1e-12f);   // F.normalize eps
  const float ik = 1.0f / fmaxf(sqrtf(sk), 1e-12f);
  union { ushort4 u; __hip_bfloat16 h[4]; } pq, pk;
  pq.h[0] = __float2bfloat16(qv.x * iq);
  pq.h[1] = __float2bfloat16(qv.y * iq);
  pq.h[2] = __float2bfloat16(qv.z * iq);
  pq.h[3] = __float2bfloat16(qv.w * iq);
  pk.h[0] = __float2bfloat16(kv.x * ik);
  pk.h[1] = __float2bfloat16(kv.y * ik);
  pk.h[2] = __float2bfloat16(kv.z * ik);
  pk.h[3] = __float2bfloat16(kv.w * ik);
  reinterpret_cast<ushort4*>(qn)[(size_t)row * (ND / 4) + lane] = pq.u;
  reinterpret_cast<ushort4*>(kn)[(size_t)row * (ND / 4) + lane] = pk.u;
  if (lane == 0) diag[row] = __expf(dp * iq * ik * TEMP_INV);  // exact fp32 diag
}

// ---------------- kernel 2: fused bf16 MFMA GEMM + exp + row/col reduce ------
// 256x256 tile, BK=64, 8 waves (2M x 4N), per-wave 128x64 (8x4 frags of 16x16).
// LDS 128KB dynamic: A0|A1|B0|B1, each 256x64 bf16 (32KB), double-buffered.
// Swizzle: LDS[row][chunk] holds global chunk (chunk ^ (row&7)); reads XOR back.
#define BM 256
#define BN 256
#define BK 64

__global__ __launch_bounds__(512, 2) void gemm_exp_reduce_kernel(
    const ushort* __restrict__ qn, const ushort* __restrict__ kn,
    float* __restrict__ rowsum, float* __restrict__ colsum) {
  extern __shared__ ushort smem[];   // 65536 ushorts = 128KB
  ushort* A0 = smem;                 // 16384 ushorts each
  ushort* A1 = smem + 16384;
  ushort* B0 = smem + 32768;
  ushort* B1 = smem + 49152;

  const int tid  = threadIdx.x;
  const int lane = tid & 63;
  const int wave = tid >> 6;          // 8 waves: 2M x 4N of 128x64 sub-tiles
  const int wr = wave >> 2;           // 0..1
  const int wc = wave & 3;            // 0..3
  const int l15 = lane & 15;
  const int lhi = lane >> 4;
  const int brow = blockIdx.y * BM;
  const int bcol = blockIdx.x * BN;

  f32x4 acc[8][4];
#pragma unroll
  for (int mf = 0; mf < 8; ++mf)
#pragma unroll
    for (int nf = 0; nf < 4; ++nf)
      acc[mf][nf] = (f32x4){0.f, 0.f, 0.f, 0.f};

  // stage one K-tile (A 256x64 + B 256x64) into (Adst,Bdst); 8 loads/thread.
  // 16B chunk f = p*512 + wave*64 + lane; row = f>>3; lds chunk = f&7 holds
  // global chunk (f&7)^(row&7)  [inverse-swizzled source, linear LDS dest].
  auto stage = [&](int kt, ushort* Adst, ushort* Bdst) {
#pragma unroll
    for (int p = 0; p < 4; ++p) {
      const int f   = p * 512 + wave * 64 + lane;
      const int row = f >> 3;
      const int gch = (f & 7) ^ (row & 7);
      GLOAD_LDS16(&qn[(size_t)(brow + row) * ND + kt * BK + gch * 8],
                  Adst + (size_t)(p * 512 + wave * 64) * 8);
      GLOAD_LDS16(&kn[(size_t)(bcol + row) * ND + kt * BK + gch * 8],
                  Bdst + (size_t)(p * 512 + wave * 64) * 8);
    }
  };

  // compute one K-tile from (Abase,Bbase): 24 ds_read_b128 + 64 MFMA per wave.
  auto compute = [&](const ushort* Abase, const ushort* Bbase) {
#pragma unroll
    for (int ks = 0; ks < 2; ++ks) {
      s16x8 af[8], bfr[4];
#pragma unroll
      for (int mf = 0; mf < 8; ++mf) {
        const int row = wr * 128 + mf * 16 + l15;
        const int ch  = (ks * 4 + lhi) ^ (row & 7);   // swizzled read
        af[mf] = *reinterpret_cast<const s16x8*>(Abase + row * 64 + ch * 8);
      }
#pragma unroll
      for (int nf = 0; nf < 4; ++nf) {
        const int row = wc * 64 + nf * 16 + l15;
        const int ch  = (ks * 4 + lhi) ^ (row & 7);
        bfr[nf] = *reinterpret_cast<const s16x8*>(Bbase + row * 64 + ch * 8);
      }
#pragma unroll
      for (int mf = 0; mf < 8; ++mf)
#pragma unroll
        for (int nf = 0; nf < 4; ++nf)
          acc[mf][nf] = __builtin_amdgcn_mfma_f32_16x16x32_bf16(
              af[mf], bfr[nf], acc[mf][nf], 0, 0, 0);
    }
  };

  // ---- counted-vmcnt double-buffered schedule over nt=4 K-tiles ----
  // vmcnt is per-wave; 8 loads per stage. Raw s_barrier (no compiler drain).
  stage(0, A0, B0);
  stage(1, A1, B1);
  asm volatile("s_waitcnt vmcnt(8)" ::: "memory");   // kt0 landed (kt1 in flight)
  __builtin_amdgcn_s_barrier();
  compute(A0, B0);
  __builtin_amdgcn_s_barrier();                      // buf0 free
  stage(2, A0, B0);
  asm volatile("s_waitcnt vmcnt(8)" ::: "memory");   // kt1 landed
  __builtin_amdgcn_s_barrier();
  compute(A1, B1);
  __builtin_amdgcn_s_barrier();                      // buf1 free
  stage(3, A1, B1);
  asm volatile("s_waitcnt vmcnt(8)" ::: "memory");   // kt2 landed
  __builtin_amdgcn_s_barrier();
  compute(A0, B0);
  asm volatile("s_waitcnt vmcnt(0)" ::: "memory");   // kt3 landed
  __builtin_amdgcn_s_barrier();
  compute(A1, B1);

  // ---- epilogue: E = exp(S/T), then row/col reductions ----
#pragma unroll
  for (int mf = 0; mf < 8; ++mf)
#pragma unroll
    for (int nf = 0; nf < 4; ++nf)
#pragma unroll
      for (int j = 0; j < 4; ++j)
        acc[mf][nf][j] = __expf(acc[mf][nf][j] * TEMP_INV);

  // C/D layout: col = lane&15, row = (lane>>4)*4 + j
#pragma unroll
  for (int mf = 0; mf < 8; ++mf) {
#pragma unroll
    for (int j = 0; j < 4; ++j) {
      float v = acc[mf][0][j] + acc[mf][1][j] + acc[mf][2][j] + acc[mf][3][j];
      v += __shfl_xor(v, 1);
      v += __shfl_xor(v, 2);
      v += __shfl_xor(v, 4);
      v += __shfl_xor(v, 8);
      if (l15 == 0) {
        const int row = brow + wr * 128 + mf * 16 + lhi * 4 + j;
        atomicAdd(&rowsum[row], v);
      }
    }
  }
#pragma unroll
  for (int nf = 0; nf < 4; ++nf) {
    float c = 0.f;
#pragma unroll
    for (int mf = 0; mf < 8; ++mf)
#pragma unroll
      for (int j = 0; j < 4; ++j)
        c += acc[mf][nf][j];
    c += __shfl_xor(c, 16);
    c += __shfl_xor(c, 32);
    if (lhi == 0) {
      const int col = bcol + wc * 64 + nf * 16 + l15;
      atomicAdd(&colsum[col], c);
    }
  }
}

// ---------------- kernel 3: final scalar loss (parallel, 16 blocks) ----------
__global__ __launch_bounds__(256) void loss_kernel(
    const float* __restrict__ diag, const float* __restrict__ rowsum,
    const float* __restrict__ colsum, float* __restrict__ out) {
  float acc = 0.f;
  for (int i = blockIdx.x * 256 + threadIdx.x; i < NB; i += 16 * 256) {
    const float d = diag[i];
    acc -= __logf(d / rowsum[i] + EPS);
    acc -= __logf(d / colsum[i] + EPS);
  }
#pragma unroll
  for (int m = 1; m < 64; m <<= 1) acc += __shfl_xor(acc, m);
  __shared__ float ls[4];
  const int wave = threadIdx.x >> 6;
  if ((threadIdx.x & 63) == 0) ls[wave] = acc;
  __syncthreads();
  if (threadIdx.x == 0)
    atomicAdd(out, (ls[0] + ls[1] + ls[2] + ls[3]) * (1.0f / NB));
}

extern "C" void kernel_launch(void* const* d_in, const int* in_sizes, int n_in,
                              void* d_out, int out_size, void* d_ws, size_t ws_size,
                              hipStream_t stream) {
  const float* q = (const float*)d_in[0];
  const float* k = (const float*)d_in[1];
  char* ws = (char*)d_ws;
  ushort* qn   = (ushort*)ws;                                   // 4 MB
  ushort* kn   = (ushort*)(ws + (size_t)NB * ND * 2);           // 4 MB
  float*  diag = (float*)(ws + (size_t)NB * ND * 4);            // 32 KB
  float*  rowsum = diag + NB;                                   // 32 KB
  float*  colsum = rowsum + NB;                                 // 32 KB
  float*  out = (float*)d_out;

  // allow 128KB dynamic LDS (host-side attribute, idempotent, capture-safe)
  (void)hipFuncSetAttribute((const void*)gemm_exp_reduce_kernel,
                            hipFuncAttributeMaxDynamicSharedMemorySize, 131072);

  norm_diag_kernel<<<NB / 4, 256, 0, stream>>>(q, k, qn, kn, diag, rowsum, out);
  gemm_exp_reduce_kernel<<<dim3(NB / BN, NB / BM), 512, 131072, stream>>>(
      qn, kn, rowsum, colsum);
  loss_kernel<<<16, 256, 0, stream>>>(diag, rowsum, colsum, out);
}

// Round 4
// 61.234 us; speedup vs baseline: 1.9511x; 1.9484x over previous
//
#include <hip/hip_runtime.h>
#include <hip/hip_bf16.h>

// SelfContrastiveLoss: loss over E = exp(qn @ kn^T / T), B=8192, D=256.
// R4: 8-phase fine interleave (T3/T4) + setprio (T5) on the verified 256^2
//     geometry + chunk-XOR swizzle (0 conflicts, R3); LDS transpose-reduce
//     epilogue (replaces 128 shfl/wave); XCD-aware block swizzle (T1).
//
// ws layout: qn bf16 4MB | kn bf16 4MB | diag 32KB | rowsum 32KB | colsum 32KB

#define NB 8192
#define ND 256

constexpr float EPS = 1e-5f;
// exp(x*20) == exp2(x * 20*log2(e))
constexpr float EXP2_SCALE = 28.853900817779268f;

typedef float f32x4 __attribute__((ext_vector_type(4)));
typedef short s16x8 __attribute__((ext_vector_type(8)));

#define GLOAD_LDS16(g, l)                                                  \
  __builtin_amdgcn_global_load_lds(                                        \
      (const __attribute__((address_space(1))) unsigned int*)(g),          \
      (__attribute__((address_space(3))) unsigned int*)(l), 16, 0, 0)

// ---------------- kernel 1: row L2-normalize -> bf16, fp32 diag, zero accums
__global__ __launch_bounds__(256) void norm_diag_kernel(
    const float* __restrict__ q, const float* __restrict__ k,
    ushort* __restrict__ qn, ushort* __restrict__ kn, float* __restrict__ diag,
    float* __restrict__ rowcol /*rowsum||colsum, 2*NB floats*/,
    float* __restrict__ out) {
  if (blockIdx.x < 64) rowcol[blockIdx.x * 256 + threadIdx.x] = 0.f;
  if (blockIdx.x == 64 && threadIdx.x == 0) out[0] = 0.f;

  const int wave = threadIdx.x >> 6;
  const int lane = threadIdx.x & 63;
  const int row = blockIdx.x * 4 + wave;          // one wave per row
  const float4* q4 = reinterpret_cast<const float4*>(q + (size_t)row * ND);
  const float4* k4 = reinterpret_cast<const float4*>(k + (size_t)row * ND);
  float4 qv = q4[lane];
  float4 kv = k4[lane];
  float sq = qv.x * qv.x + qv.y * qv.y + qv.z * qv.z + qv.w * qv.w;
  float sk = kv.x * kv.x + kv.y * kv.y + kv.z * kv.z + kv.w * kv.w;
  float dp = qv.x * kv.x + qv.y * kv.y + qv.z * kv.z + qv.w * kv.w;
#pragma unroll
  for (int m = 1; m < 64; m <<= 1) {
    sq += __shfl_xor(sq, m);
    sk += __shfl_xor(sk, m);
    dp += __shfl_xor(dp, m);
  }
  const float iq = 1.0f / fmaxf(sqrtf(sq), 1e-12f);   // F.normalize eps
  const float ik = 1.0f / fmaxf(sqrtf(sk), 1e-12f);
  union { ushort4 u; __hip_bfloat16 h[4]; } pq, pk;
  pq.h[0] = __float2bfloat16(qv.x * iq);
  pq.h[1] = __float2bfloat16(qv.y * iq);
  pq.h[2] = __float2bfloat16(qv.z * iq);
  pq.h[3] = __float2bfloat16(qv.w * iq);
  pk.h[0] = __float2bfloat16(kv.x * ik);
  pk.h[1] = __float2bfloat16(kv.y * ik);
  pk.h[2] = __float2bfloat16(kv.z * ik);
  pk.h[3] = __float2bfloat16(kv.w * ik);
  reinterpret_cast<ushort4*>(qn)[(size_t)row * (ND / 4) + lane] = pq.u;
  reinterpret_cast<ushort4*>(kn)[(size_t)row * (ND / 4) + lane] = pk.u;
  if (lane == 0) diag[row] = __expf(dp * iq * ik * 20.0f);  // exact fp32 diag
}

// ---------------- kernel 2: fused bf16 MFMA GEMM + exp + row/col reduce ------
// 256x256 tile, BK=64, 8 waves (2M x 4N), per-wave 128x64 (8x4 frags of 16x16).
// LDS 128KB dynamic: A0|A1|B0|B1 (32KB each), double-buffered over K-tiles.
// Chunk swizzle: LDS[row][c] holds global chunk c^(row&7); reads XOR back.
#define BM 256
#define BN 256

__global__ __launch_bounds__(512, 2) void gemm_exp_reduce_kernel(
    const ushort* __restrict__ qn, const ushort* __restrict__ kn,
    float* __restrict__ rowsum, float* __restrict__ colsum) {
  extern __shared__ ushort smem[];   // 65536 ushorts = 128KB
  ushort* A0 = smem;                 // 16384 ushorts each
  ushort* A1 = smem + 16384;
  ushort* B0 = smem + 32768;
  ushort* B1 = smem + 49152;

  const int tid  = threadIdx.x;
  const int lane = tid & 63;
  const int wave = tid >> 6;          // 8 waves: 2M x 4N of 128x64 sub-tiles
  const int wr = wave >> 2;           // 0..1
  const int wc = wave & 3;            // 0..3
  const int l15 = lane & 15;
  const int lhi = lane >> 4;

  // XCD-aware swizzle: 1024 blocks, XCD x gets contiguous logical range
  const int lid = blockIdx.y * 32 + blockIdx.x;
  const int swz = (lid & 7) * 128 + (lid >> 3);
  const int brow = (swz >> 5) * BM;
  const int bcol = (swz & 31) * BN;

  f32x4 acc[8][4];
#pragma unroll
  for (int mf = 0; mf < 8; ++mf)
#pragma unroll
    for (int nf = 0; nf < 4; ++nf)
      acc[mf][nf] = (f32x4){0.f, 0.f, 0.f, 0.f};

  // stage half: 4 gload_lds per thread = one 256x64 bf16 matrix tile (32KB).
  auto stageA = [&](int kt, ushort* Adst) {
#pragma unroll
    for (int p = 0; p < 4; ++p) {
      const int f   = p * 512 + wave * 64 + lane;
      const int row = f >> 3;
      const int gch = (f & 7) ^ (row & 7);
      GLOAD_LDS16(&qn[(size_t)(brow + row) * ND + kt * 64 + gch * 8],
                  Adst + (size_t)(p * 512 + wave * 64) * 8);
    }
  };
  auto stageB = [&](int kt, ushort* Bdst) {
#pragma unroll
    for (int p = 0; p < 4; ++p) {
      const int f   = p * 512 + wave * 64 + lane;
      const int row = f >> 3;
      const int gch = (f & 7) ^ (row & 7);
      GLOAD_LDS16(&kn[(size_t)(bcol + row) * ND + kt * 64 + gch * 8],
                  Bdst + (size_t)(p * 512 + wave * 64) * 8);
    }
  };

  // one K-tile = 4 phases of {ds_read subtile | stage next | bar | MFMA x16 | bar}
  auto tile = [&](const ushort* Ab, const ushort* Bb, ushort* An, ushort* Bn,
                  int ktn, bool do_stage) {
    s16x8 af[4], bfr[4];
    // ---- phase 0: ks=0, mf 0-3 (8 ds_reads) ; stage next A ----
#pragma unroll
    for (int nf = 0; nf < 4; ++nf) {
      const int r = wc * 64 + nf * 16 + l15;
      bfr[nf] = *reinterpret_cast<const s16x8*>(Bb + r * 64 + (lhi ^ (r & 7)) * 8);
    }
#pragma unroll
    for (int mf = 0; mf < 4; ++mf) {
      const int r = wr * 128 + mf * 16 + l15;
      af[mf] = *reinterpret_cast<const s16x8*>(Ab + r * 64 + (lhi ^ (r & 7)) * 8);
    }
    if (do_stage) stageA(ktn, An);
    __builtin_amdgcn_s_barrier();
    asm volatile("s_waitcnt lgkmcnt(0)" ::: "memory");
    __builtin_amdgcn_s_setprio(1);
#pragma unroll
    for (int mf = 0; mf < 4; ++mf)
#pragma unroll
      for (int nf = 0; nf < 4; ++nf)
        acc[mf][nf] = __builtin_amdgcn_mfma_f32_16x16x32_bf16(
            af[mf], bfr[nf], acc[mf][nf], 0, 0, 0);
    __builtin_amdgcn_s_setprio(0);
    __builtin_amdgcn_s_barrier();
    // ---- phase 1: ks=0, mf 4-7 (4 ds_reads) ; stage next B ----
#pragma unroll
    for (int mf = 0; mf < 4; ++mf) {
      const int r = wr * 128 + (mf + 4) * 16 + l15;
      af[mf] = *reinterpret_cast<const s16x8*>(Ab + r * 64 + (lhi ^ (r & 7)) * 8);
    }
    if (do_stage) stageB(ktn, Bn);
    __builtin_amdgcn_s_barrier();
    asm volatile("s_waitcnt lgkmcnt(0)" ::: "memory");
    __builtin_amdgcn_s_setprio(1);
#pragma unroll
    for (int mf = 0; mf < 4; ++mf)
#pragma unroll
      for (int nf = 0; nf < 4; ++nf)
        acc[mf + 4][nf] = __builtin_amdgcn_mfma_f32_16x16x32_bf16(
            af[mf], bfr[nf], acc[mf + 4][nf], 0, 0, 0);
    __builtin_amdgcn_s_setprio(0);
    __builtin_amdgcn_s_barrier();
    // ---- phase 2: ks=1, mf 0-3 (8 ds_reads) ----
#pragma unroll
    for (int nf = 0; nf < 4; ++nf) {
      const int r = wc * 64 + nf * 16 + l15;
      bfr[nf] = *reinterpret_cast<const s16x8*>(Bb + r * 64 + ((4 + lhi) ^ (r & 7)) * 8);
    }
#pragma unroll
    for (int mf = 0; mf < 4; ++mf) {
      const int r = wr * 128 + mf * 16 + l15;
      af[mf] = *reinterpret_cast<const s16x8*>(Ab + r * 64 + ((4 + lhi) ^ (r & 7)) * 8);
    }
    __builtin_amdgcn_s_barrier();
    asm volatile("s_waitcnt lgkmcnt(0)" ::: "memory");
    __builtin_amdgcn_s_setprio(1);
#pragma unroll
    for (int mf = 0; mf < 4; ++mf)
#pragma unroll
      for (int nf = 0; nf < 4; ++nf)
        acc[mf][nf] = __builtin_amdgcn_mfma_f32_16x16x32_bf16(
            af[mf], bfr[nf], acc[mf][nf], 0, 0, 0);
    __builtin_amdgcn_s_setprio(0);
    __builtin_amdgcn_s_barrier();
    // ---- phase 3: ks=1, mf 4-7 (4 ds_reads) ----
#pragma unroll
    for (int mf = 0; mf < 4; ++mf) {
      const int r = wr * 128 + (mf + 4) * 16 + l15;
      af[mf] = *reinterpret_cast<const s16x8*>(Ab + r * 64 + ((4 + lhi) ^ (r & 7)) * 8);
    }
    __builtin_amdgcn_s_barrier();
    asm volatile("s_waitcnt lgkmcnt(0)" ::: "memory");
    __builtin_amdgcn_s_setprio(1);
#pragma unroll
    for (int mf = 0; mf < 4; ++mf)
#pragma unroll
      for (int nf = 0; nf < 4; ++nf)
        acc[mf + 4][nf] = __builtin_amdgcn_mfma_f32_16x16x32_bf16(
            af[mf], bfr[nf], acc[mf + 4][nf], 0, 0, 0);
    __builtin_amdgcn_s_setprio(0);
    __builtin_amdgcn_s_barrier();
  };

#define WAIT_ALL()                                           \
  asm volatile("s_waitcnt vmcnt(0)" ::: "memory");           \
  __builtin_amdgcn_s_barrier();

  // prologue: tile 0 into buf0; tiles 1..3 staged inside previous tile's phases
  stageA(0, A0);
  stageB(0, B0);
  WAIT_ALL();
  tile(A0, B0, A1, B1, 1, true);
  WAIT_ALL();
  tile(A1, B1, A0, B0, 2, true);
  WAIT_ALL();
  tile(A0, B0, A1, B1, 3, true);
  WAIT_ALL();
  tile(A1, B1, A0, B0, 0, false);

  // ---- epilogue: E = exp2(S*20*log2e), LDS transpose-reduce, 1 atomic/entry
#pragma unroll
  for (int mf = 0; mf < 8; ++mf)
#pragma unroll
    for (int nf = 0; nf < 4; ++nf)
#pragma unroll
      for (int j = 0; j < 4; ++j)
        acc[mf][nf][j] = exp2f(acc[mf][nf][j] * EXP2_SCALE);

  __syncthreads();                       // compute done; reuse smem
  float* RS = reinterpret_cast<float*>(smem);          // [256][68] row partials
  float* CS = RS + 256 * 68;                           // [256][12] col partials

  // rowsum partials: per (row, col16) one value; col = wc*16+l15
#pragma unroll
  for (int mf = 0; mf < 8; ++mf) {
    f32x4 s = acc[mf][0] + acc[mf][1] + acc[mf][2] + acc[mf][3];
    const int rowb = wr * 128 + mf * 16 + lhi * 4;
    const int col  = wc * 16 + l15;
#pragma unroll
    for (int j = 0; j < 4; ++j) RS[(rowb + j) * 68 + col] = s[j];
  }
  // colsum partials: per (col, wr*4+lhi) one value
#pragma unroll
  for (int nf = 0; nf < 4; ++nf) {
    float cs = 0.f;
#pragma unroll
    for (int mf = 0; mf < 8; ++mf)
#pragma unroll
      for (int j = 0; j < 4; ++j) cs += acc[mf][nf][j];
    CS[(wc * 64 + nf * 16 + l15) * 12 + wr * 4 + lhi] = cs;
  }
  __syncthreads();
  {
    const int r = tid >> 1, h = tid & 1;   // 2 threads per row/col entry
    f32x4 p = (f32x4){0.f, 0.f, 0.f, 0.f};
#pragma unroll
    for (int c = 0; c < 8; ++c)
      p += *reinterpret_cast<const f32x4*>(&RS[r * 68 + h * 32 + c * 4]);
    float s = p[0] + p[1] + p[2] + p[3];
    s += __shfl_xor(s, 1);
    f32x4 pc = *reinterpret_cast<const f32x4*>(&CS[r * 12 + h * 4]);
    float sc = pc[0] + pc[1] + pc[2] + pc[3];
    sc += __shfl_xor(sc, 1);
    if (h == 0) {
      atomicAdd(&rowsum[brow + r], s);
      atomicAdd(&colsum[bcol + r], sc);
    }
  }
#undef WAIT_ALL
}

// ---------------- kernel 3: final scalar loss (parallel, 16 blocks) ----------
__global__ __launch_bounds__(256) void loss_kernel(
    const float* __restrict__ diag, const float* __restrict__ rowsum,
    const float* __restrict__ colsum, float* __restrict__ out) {
  float acc = 0.f;
  for (int i = blockIdx.x * 256 + threadIdx.x; i < NB; i += 16 * 256) {
    const float d = diag[i];
    acc -= __logf(d / rowsum[i] + EPS);
    acc -= __logf(d / colsum[i] + EPS);
  }
#pragma unroll
  for (int m = 1; m < 64; m <<= 1) acc += __shfl_xor(acc, m);
  __shared__ float ls[4];
  const int wave = threadIdx.x >> 6;
  if ((threadIdx.x & 63) == 0) ls[wave] = acc;
  __syncthreads();
  if (threadIdx.x == 0)
    atomicAdd(out, (ls[0] + ls[1] + ls[2] + ls[3]) * (1.0f / NB));
}

extern "C" void kernel_launch(void* const* d_in, const int* in_sizes, int n_in,
                              void* d_out, int out_size, void* d_ws, size_t ws_size,
                              hipStream_t stream) {
  const float* q = (const float*)d_in[0];
  const float* k = (const float*)d_in[1];
  char* ws = (char*)d_ws;
  ushort* qn   = (ushort*)ws;                                   // 4 MB
  ushort* kn   = (ushort*)(ws + (size_t)NB * ND * 2);           // 4 MB
  float*  diag = (float*)(ws + (size_t)NB * ND * 4);            // 32 KB
  float*  rowsum = diag + NB;                                   // 32 KB
  float*  colsum = rowsum + NB;                                 // 32 KB
  float*  out = (float*)d_out;

  (void)hipFuncSetAttribute((const void*)gemm_exp_reduce_kernel,
                            hipFuncAttributeMaxDynamicSharedMemorySize, 131072);

  norm_diag_kernel<<<NB / 4, 256, 0, stream>>>(q, k, qn, kn, diag, rowsum, out);
  gemm_exp_reduce_kernel<<<dim3(NB / BN, NB / BM), 512, 131072, stream>>>(
      qn, kn, rowsum, colsum);
  loss_kernel<<<16, 256, 0, stream>>>(diag, rowsum, colsum, out);
}

// Round 5
// 60.776 us; speedup vs baseline: 1.9658x; 1.0075x over previous
//
#include <hip/hip_runtime.h>
#include <hip/hip_bf16.h>

// SelfContrastiveLoss: loss over E = exp(qn @ kn^T / T), B=8192, D=256.
// R5: register-load software pipelining — each phase issues the NEXT phase's
//     ds_reads before its MFMA cluster (counted lgkm waits become free);
//     tile-boundary vmcnt+barrier moved into phase 3 so next-tile reads are
//     also hoisted. 2 fragment register banks. XCD map -> 16x8 regions (L2-fit).
//
// ws layout: qn bf16 4MB | kn bf16 4MB | diag 32KB | rowsum 32KB | colsum 32KB

#define NB 8192
#define ND 256

constexpr float EPS = 1e-5f;
// exp(x*20) == exp2(x * 20*log2(e))
constexpr float EXP2_SCALE = 28.853900817779268f;

typedef float f32x4 __attribute__((ext_vector_type(4)));
typedef short s16x8 __attribute__((ext_vector_type(8)));

#define GLOAD_LDS16(g, l)                                                  \
  __builtin_amdgcn_global_load_lds(                                        \
      (const __attribute__((address_space(1))) unsigned int*)(g),          \
      (__attribute__((address_space(3))) unsigned int*)(l), 16, 0, 0)

#define BAR()    __builtin_amdgcn_s_barrier()
#define SCHED0() __builtin_amdgcn_sched_barrier(0)
#define PRIO(x)  __builtin_amdgcn_s_setprio(x)

// ---------------- kernel 1: row L2-normalize -> bf16, fp32 diag, zero accums
__global__ __launch_bounds__(256) void norm_diag_kernel(
    const float* __restrict__ q, const float* __restrict__ k,
    ushort* __restrict__ qn, ushort* __restrict__ kn, float* __restrict__ diag,
    float* __restrict__ rowcol /*rowsum||colsum, 2*NB floats*/,
    float* __restrict__ out) {
  if (blockIdx.x < 64) rowcol[blockIdx.x * 256 + threadIdx.x] = 0.f;
  if (blockIdx.x == 64 && threadIdx.x == 0) out[0] = 0.f;

  const int wave = threadIdx.x >> 6;
  const int lane = threadIdx.x & 63;
  const int row = blockIdx.x * 4 + wave;          // one wave per row
  const float4* q4 = reinterpret_cast<const float4*>(q + (size_t)row * ND);
  const float4* k4 = reinterpret_cast<const float4*>(k + (size_t)row * ND);
  float4 qv = q4[lane];
  float4 kv = k4[lane];
  float sq = qv.x * qv.x + qv.y * qv.y + qv.z * qv.z + qv.w * qv.w;
  float sk = kv.x * kv.x + kv.y * kv.y + kv.z * kv.z + kv.w * kv.w;
  float dp = qv.x * kv.x + qv.y * kv.y + qv.z * kv.z + qv.w * kv.w;
#pragma unroll
  for (int m = 1; m < 64; m <<= 1) {
    sq += __shfl_xor(sq, m);
    sk += __shfl_xor(sk, m);
    dp += __shfl_xor(dp, m);
  }
  const float iq = 1.0f / fmaxf(sqrtf(sq), 1e-12f);   // F.normalize eps
  const float ik = 1.0f / fmaxf(sqrtf(sk), 1e-12f);
  union { ushort4 u; __hip_bfloat16 h[4]; } pq, pk;
  pq.h[0] = __float2bfloat16(qv.x * iq);
  pq.h[1] = __float2bfloat16(qv.y * iq);
  pq.h[2] = __float2bfloat16(qv.z * iq);
  pq.h[3] = __float2bfloat16(qv.w * iq);
  pk.h[0] = __float2bfloat16(kv.x * ik);
  pk.h[1] = __float2bfloat16(kv.y * ik);
  pk.h[2] = __float2bfloat16(kv.z * ik);
  pk.h[3] = __float2bfloat16(kv.w * ik);
  reinterpret_cast<ushort4*>(qn)[(size_t)row * (ND / 4) + lane] = pq.u;
  reinterpret_cast<ushort4*>(kn)[(size_t)row * (ND / 4) + lane] = pk.u;
  if (lane == 0) diag[row] = __expf(dp * iq * ik * 20.0f);  // exact fp32 diag
}

// ---------------- kernel 2: fused bf16 MFMA GEMM + exp + row/col reduce ------
// 256x256 tile, BK=64, 8 waves (2M x 4N), per-wave 128x64 (8x4 frags of 16x16).
// LDS 128KB dynamic: A0|A1|B0|B1 (32KB each), double-buffered over K-tiles.
// Chunk swizzle: LDS[row][c] holds global chunk c^(row&7); reads XOR back.
#define BM 256
#define BN 256

__global__ __launch_bounds__(512, 2) void gemm_exp_reduce_kernel(
    const ushort* __restrict__ qn, const ushort* __restrict__ kn,
    float* __restrict__ rowsum, float* __restrict__ colsum) {
  extern __shared__ ushort smem[];   // 65536 ushorts = 128KB
  ushort* A0 = smem;                 // 16384 ushorts each
  ushort* A1 = smem + 16384;
  ushort* B0 = smem + 32768;
  ushort* B1 = smem + 49152;

  const int tid  = threadIdx.x;
  const int lane = tid & 63;
  const int wave = tid >> 6;          // 8 waves: 2M x 4N of 128x64 sub-tiles
  const int wr = wave >> 2;           // 0..1
  const int wc = wave & 3;            // 0..3
  const int l15 = lane & 15;
  const int lhi = lane >> 4;

  // XCD-aware map: xcd = lid%8 gets a 16x8-tile region (A 2MB + B 1MB < 4MB L2)
  const int lid = blockIdx.y * 32 + blockIdx.x;
  const int xcd = lid & 7;
  const int j   = lid >> 3;                       // 0..127 within region
  const int brow = ((xcd >> 2) * 16 + (j >> 3)) * BM;
  const int bcol = ((xcd & 3) * 8 + (j & 7)) * BN;

  f32x4 acc[8][4];
#pragma unroll
  for (int mf = 0; mf < 8; ++mf)
#pragma unroll
    for (int nf = 0; nf < 4; ++nf)
      acc[mf][nf] = (f32x4){0.f, 0.f, 0.f, 0.f};

  auto stageA = [&](int kt, ushort* Adst) {
#pragma unroll
    for (int p = 0; p < 4; ++p) {
      const int f   = p * 512 + wave * 64 + lane;
      const int row = f >> 3;
      const int gch = (f & 7) ^ (row & 7);
      GLOAD_LDS16(&qn[(size_t)(brow + row) * ND + kt * 64 + gch * 8],
                  Adst + (size_t)(p * 512 + wave * 64) * 8);
    }
  };
  auto stageB = [&](int kt, ushort* Bdst) {
#pragma unroll
    for (int p = 0; p < 4; ++p) {
      const int f   = p * 512 + wave * 64 + lane;
      const int row = f >> 3;
      const int gch = (f & 7) ^ (row & 7);
      GLOAD_LDS16(&kn[(size_t)(bcol + row) * ND + kt * 64 + gch * 8],
                  Bdst + (size_t)(p * 512 + wave * 64) * 8);
    }
  };

  // fragment loads (swizzled reads)
  auto ldB = [&](s16x8* dst, const ushort* base, int ks) {
#pragma unroll
    for (int nf = 0; nf < 4; ++nf) {
      const int r = wc * 64 + nf * 16 + l15;
      dst[nf] = *reinterpret_cast<const s16x8*>(
          base + r * 64 + ((ks * 4 + lhi) ^ (r & 7)) * 8);
    }
  };
  auto ldA = [&](s16x8* dst, const ushort* base, int half, int ks) {
#pragma unroll
    for (int mf = 0; mf < 4; ++mf) {
      const int r = wr * 128 + (half * 4 + mf) * 16 + l15;
      dst[mf] = *reinterpret_cast<const s16x8*>(
          base + r * 64 + ((ks * 4 + lhi) ^ (r & 7)) * 8);
    }
  };
  auto mm = [&](const s16x8* a, const s16x8* b, int half) {
#pragma unroll
    for (int mf = 0; mf < 4; ++mf)
#pragma unroll
      for (int nf = 0; nf < 4; ++nf)
        acc[half * 4 + mf][nf] = __builtin_amdgcn_mfma_f32_16x16x32_bf16(
            a[mf], b[nf], acc[half * 4 + mf][nf], 0, 0, 0);
  };

  s16x8 afA[4], afB[4], bfA[4], bfB[4];

  // One K-tile, reads pipelined one phase ahead. On entry: afA(ks0,m0-3) and
  // bfA(ks0) are loaded (issued during the previous phase/prologue).
  auto tile = [&](const ushort* Ab, const ushort* Bb,
                  ushort* Asn, ushort* Bsn, int ktn, bool do_stage,
                  const ushort* Abn, const ushort* Bbn, bool read_next) {
    // ph0: issue R1 (afB ks0 m4-7); stage next A; MFMA ks0 m0-3
    ldA(afB, Ab, 1, 0);
    if (do_stage) stageA(ktn, Asn);
    BAR(); SCHED0(); PRIO(1); mm(afA, bfA, 0); PRIO(0); SCHED0(); BAR();
    // ph1: issue R2 (bfB ks1 + afA ks1 m0-3); stage next B; MFMA ks0 m4-7
    ldB(bfB, Bb, 1);
    ldA(afA, Ab, 0, 1);
    if (do_stage) stageB(ktn, Bsn);
    BAR(); SCHED0(); PRIO(1); mm(afB, bfA, 1); PRIO(0); SCHED0(); BAR();
    // ph2: issue R3 (afB ks1 m4-7); MFMA ks1 m0-3
    ldA(afB, Ab, 1, 1);
    BAR(); SCHED0(); PRIO(1); mm(afA, bfB, 0); PRIO(0); SCHED0(); BAR();
    // ph3: boundary fence (stage of next tile landed) + next tile R0; MFMA ks1 m4-7
    if (read_next) {
      asm volatile("s_waitcnt vmcnt(0)" ::: "memory");
      BAR();
      ldB(bfA, Bbn, 0);
      ldA(afA, Abn, 0, 0);
    }
    SCHED0(); PRIO(1); mm(afB, bfB, 1); PRIO(0); SCHED0();
    BAR();
  };

  // prologue: stage tile 0, drain, preload R0
  stageA(0, A0);
  stageB(0, B0);
  asm volatile("s_waitcnt vmcnt(0)" ::: "memory");
  BAR();
  ldB(bfA, B0, 0);
  ldA(afA, A0, 0, 0);

  tile(A0, B0, A1, B1, 1, true,  A1, B1, true);
  tile(A1, B1, A0, B0, 2, true,  A0, B0, true);
  tile(A0, B0, A1, B1, 3, true,  A1, B1, true);
  tile(A1, B1, A0, B0, 0, false, A0, B0, false);

  // ---- epilogue: E = exp2(S*20*log2e), LDS transpose-reduce, 1 atomic/entry
#pragma unroll
  for (int mf = 0; mf < 8; ++mf)
#pragma unroll
    for (int nf = 0; nf < 4; ++nf)
#pragma unroll
      for (int j2 = 0; j2 < 4; ++j2)
        acc[mf][nf][j2] = exp2f(acc[mf][nf][j2] * EXP2_SCALE);

  __syncthreads();                       // compute done; reuse smem
  float* RS = reinterpret_cast<float*>(smem);          // [256][68] row partials
  float* CS = RS + 256 * 68;                           // [256][12] col partials

  // rowsum partials: per (row, col16) one value; col = wc*16+l15
#pragma unroll
  for (int mf = 0; mf < 8; ++mf) {
    f32x4 s = acc[mf][0] + acc[mf][1] + acc[mf][2] + acc[mf][3];
    const int rowb = wr * 128 + mf * 16 + lhi * 4;
    const int col  = wc * 16 + l15;
#pragma unroll
    for (int j2 = 0; j2 < 4; ++j2) RS[(rowb + j2) * 68 + col] = s[j2];
  }
  // colsum partials: per (col, wr*4+lhi) one value
#pragma unroll
  for (int nf = 0; nf < 4; ++nf) {
    float cs = 0.f;
#pragma unroll
    for (int mf = 0; mf < 8; ++mf)
#pragma unroll
      for (int j2 = 0; j2 < 4; ++j2) cs += acc[mf][nf][j2];
    CS[(wc * 64 + nf * 16 + l15) * 12 + wr * 4 + lhi] = cs;
  }
  __syncthreads();
  {
    const int r = tid >> 1, h = tid & 1;   // 2 threads per row/col entry
    f32x4 p = (f32x4){0.f, 0.f, 0.f, 0.f};
#pragma unroll
    for (int c = 0; c < 8; ++c)
      p += *reinterpret_cast<const f32x4*>(&RS[r * 68 + h * 32 + c * 4]);
    float s = p[0] + p[1] + p[2] + p[3];
    s += __shfl_xor(s, 1);
    f32x4 pc = *reinterpret_cast<const f32x4*>(&CS[r * 12 + h * 4]);
    float sc = pc[0] + pc[1] + pc[2] + pc[3];
    sc += __shfl_xor(sc, 1);
    if (h == 0) {
      atomicAdd(&rowsum[brow + r], s);
      atomicAdd(&colsum[bcol + r], sc);
    }
  }
}

// ---------------- kernel 3: final scalar loss (parallel, 32 blocks) ----------
__global__ __launch_bounds__(256) void loss_kernel(
    const float* __restrict__ diag, const float* __restrict__ rowsum,
    const float* __restrict__ colsum, float* __restrict__ out) {
  float acc = 0.f;
  for (int i = blockIdx.x * 256 + threadIdx.x; i < NB; i += 32 * 256) {
    const float d = diag[i];
    acc -= __logf(d / rowsum[i] + EPS);
    acc -= __logf(d / colsum[i] + EPS);
  }
#pragma unroll
  for (int m = 1; m < 64; m <<= 1) acc += __shfl_xor(acc, m);
  __shared__ float ls[4];
  const int wave = threadIdx.x >> 6;
  if ((threadIdx.x & 63) == 0) ls[wave] = acc;
  __syncthreads();
  if (threadIdx.x == 0)
    atomicAdd(out, (ls[0] + ls[1] + ls[2] + ls[3]) * (1.0f / NB));
}

extern "C" void kernel_launch(void* const* d_in, const int* in_sizes, int n_in,
                              void* d_out, int out_size, void* d_ws, size_t ws_size,
                              hipStream_t stream) {
  const float* q = (const float*)d_in[0];
  const float* k = (const float*)d_in[1];
  char* ws = (char*)d_ws;
  ushort* qn   = (ushort*)ws;                                   // 4 MB
  ushort* kn   = (ushort*)(ws + (size_t)NB * ND * 2);           // 4 MB
  float*  diag = (float*)(ws + (size_t)NB * ND * 4);            // 32 KB
  float*  rowsum = diag + NB;                                   // 32 KB
  float*  colsum = rowsum + NB;                                 // 32 KB
  float*  out = (float*)d_out;

  (void)hipFuncSetAttribute((const void*)gemm_exp_reduce_kernel,
                            hipFuncAttributeMaxDynamicSharedMemorySize, 131072);

  norm_diag_kernel<<<NB / 4, 256, 0, stream>>>(q, k, qn, kn, diag, rowsum, out);
  gemm_exp_reduce_kernel<<<dim3(NB / BN, NB / BM), 512, 131072, stream>>>(
      qn, kn, rowsum, colsum);
  loss_kernel<<<32, 256, 0, stream>>>(diag, rowsum, colsum, out);
}